// Round 4
// baseline (420.505 us; speedup 1.0000x reference)
//
#include <hip/hip_runtime.h>
#include <hip/hip_bf16.h>
#include <hip/hip_fp16.h>
#include <math.h>

constexpr int NTOK = 524288;   // T
constexpr int NB   = 4096;     // B
constexpr int H    = 512;
constexpr float EPS = 1e-5f;

typedef _Float16 half8 __attribute__((ext_vector_type(8)));
typedef float f32x4 __attribute__((ext_vector_type(4)));
struct h4 { __half2 a, b; };   // 8 bytes = 4 halves

// ---------------------------------------------------------------------------
// K-1: segment bounds scatter.  bounds[b] = first index i with seg[i] >= b.
// Replaces per-block binary search (2x19 dependent global loads ~6us/block).
// ---------------------------------------------------------------------------
__global__ __launch_bounds__(256) void k_seg_bounds(
    const int* __restrict__ seg, int* __restrict__ bounds) {
  const int i = blockIdx.x * 256 + threadIdx.x;
  const int s = seg[i];
  const int sp = (i == 0) ? -1 : seg[i - 1];
  for (int b = sp + 1; b <= s; ++b) bounds[b] = i;
  if (i == NTOK - 1) {
    for (int b = s + 1; b <= NB; ++b) bounds[b] = NTOK;
  }
}

// ---------------------------------------------------------------------------
// K0: fp32 -> fp16 convert (emb [big] and W1 [tiny]).
// ---------------------------------------------------------------------------
__global__ __launch_bounds__(256) void k_convert(
    const float* __restrict__ src, h4* __restrict__ dst) {
  size_t i = (size_t)blockIdx.x * 256 + threadIdx.x;
  float4 v = ((const float4*)src)[i];
  h4 o;
  o.a = __floats2half2_rn(v.x, v.y);
  o.b = __floats2half2_rn(v.z, v.w);
  dst[i] = o;
}

// ---------------------------------------------------------------------------
// K1: fused gather + segment mean (fp16 table, fp32 accum, fp16 bow out).
// 256 threads = 4 token-groups x 64 lanes (16 B/lane = full 1 KB row).
// 8-deep unroll -> 32 rows in flight per block.
// ---------------------------------------------------------------------------
__global__ __launch_bounds__(256) void k_gather_mean(
    const int* __restrict__ tokens, const int* __restrict__ bounds,
    const half8* __restrict__ embh, half8* __restrict__ bow_h) {
  const int b = blockIdx.x;
  const int start = bounds[b];
  const int end   = bounds[b + 1];

  const int tid = threadIdx.x;
  const int lane = tid & 63;
  const int g = tid >> 6;

  float acc[8] = {};
  int i = start + g;
  for (; i + 28 < end; i += 32) {
    half8 v0 = embh[(size_t)tokens[i]      * 64 + lane];
    half8 v1 = embh[(size_t)tokens[i + 4]  * 64 + lane];
    half8 v2 = embh[(size_t)tokens[i + 8]  * 64 + lane];
    half8 v3 = embh[(size_t)tokens[i + 12] * 64 + lane];
    half8 v4 = embh[(size_t)tokens[i + 16] * 64 + lane];
    half8 v5 = embh[(size_t)tokens[i + 20] * 64 + lane];
    half8 v6 = embh[(size_t)tokens[i + 24] * 64 + lane];
    half8 v7 = embh[(size_t)tokens[i + 28] * 64 + lane];
#pragma unroll
    for (int j = 0; j < 8; ++j)
      acc[j] += ((float)v0[j] + (float)v1[j]) + ((float)v2[j] + (float)v3[j]) +
                ((float)v4[j] + (float)v5[j]) + ((float)v6[j] + (float)v7[j]);
  }
  for (; i < end; i += 4) {
    half8 v0 = embh[(size_t)tokens[i] * 64 + lane];
#pragma unroll
    for (int j = 0; j < 8; ++j) acc[j] += (float)v0[j];
  }

  __shared__ float part[3][64][9];   // +1 pad breaks bank aliasing
  if (g > 0) {
#pragma unroll
    for (int j = 0; j < 8; ++j) part[g - 1][lane][j] = acc[j];
  }
  __syncthreads();
  if (g == 0) {
    const int cnt = end - start;
    const float s = 1.0f / (float)(cnt > 0 ? cnt : 1);
    half8 o;
#pragma unroll
    for (int j = 0; j < 8; ++j) {
      float v = acc[j] + part[0][lane][j] + part[1][lane][j] + part[2][lane][j];
      o[j] = (_Float16)(v * s);
    }
    bow_h[(size_t)b * 64 + lane] = o;
  }
}

// ---------------------------------------------------------------------------
// K2: z = bow @ W1^T + b1 via fp16 MFMA, fp32 accum.  No LDS; frags from L2.
// ---------------------------------------------------------------------------
__global__ __launch_bounds__(256) void k_gemm_mfma(
    const _Float16* __restrict__ A,   // bow_h [NB][H]
    const _Float16* __restrict__ Bw,  // W1h   [H][H]
    const float* __restrict__ b1, float* __restrict__ C) {
  const int tid = threadIdx.x;
  const int lane = tid & 63;
  const int gw = blockIdx.x * 4 + (tid >> 6);   // 2048 waves total
  const int m0 = (gw >> 3) * 16;                // 256 m-tiles
  const int n0 = (gw & 7) * 64;                 // 8 n-groups
  const int l15 = lane & 15, quad = lane >> 4;

  f32x4 acc0 = {}, acc1 = {}, acc2 = {}, acc3 = {};
  const _Float16* ap = A + (size_t)(m0 + l15) * H + quad * 8;
  const _Float16* bp = Bw + (size_t)(n0 + l15) * H + quad * 8;

#pragma unroll
  for (int k = 0; k < H; k += 32) {
    half8 af  = *(const half8*)(ap + k);
    half8 bf0 = *(const half8*)(bp + k);
    half8 bf1 = *(const half8*)(bp + 16 * H + k);
    half8 bf2 = *(const half8*)(bp + 32 * H + k);
    half8 bf3 = *(const half8*)(bp + 48 * H + k);
    acc0 = __builtin_amdgcn_mfma_f32_16x16x32_f16(af, bf0, acc0, 0, 0, 0);
    acc1 = __builtin_amdgcn_mfma_f32_16x16x32_f16(af, bf1, acc1, 0, 0, 0);
    acc2 = __builtin_amdgcn_mfma_f32_16x16x32_f16(af, bf2, acc2, 0, 0, 0);
    acc3 = __builtin_amdgcn_mfma_f32_16x16x32_f16(af, bf3, acc3, 0, 0, 0);
  }

  const float bn0v = b1[n0 + l15];
  const float bn1v = b1[n0 + 16 + l15];
  const float bn2v = b1[n0 + 32 + l15];
  const float bn3v = b1[n0 + 48 + l15];
  float* crow = C + (size_t)(m0 + quad * 4) * H + n0 + l15;
#pragma unroll
  for (int r = 0; r < 4; ++r) {
    crow[(size_t)r * H]      = acc0[r] + bn0v;
    crow[(size_t)r * H + 16] = acc1[r] + bn1v;
    crow[(size_t)r * H + 32] = acc2[r] + bn2v;
    crow[(size_t)r * H + 48] = acc3[r] + bn3v;
  }
}

// ---------------------------------------------------------------------------
// K3a: per-64-row-block partial column sums / sumsq of z.
// ---------------------------------------------------------------------------
__global__ __launch_bounds__(256) void k_colstats(
    const float* __restrict__ z, float* __restrict__ ps, float* __restrict__ pss) {
  const int blk = blockIdx.x;
  const int c0 = threadIdx.x * 2;
  const int r0 = blk * 64;
  float s0 = 0, s1 = 0, q0 = 0, q1 = 0;
  for (int r = 0; r < 64; ++r) {
    float2 v = *(const float2*)&z[(size_t)(r0 + r) * H + c0];
    s0 += v.x; s1 += v.y;
    q0 += v.x * v.x; q1 += v.y * v.y;
  }
  ps[blk * H + c0] = s0; ps[blk * H + c0 + 1] = s1;
  pss[blk * H + c0] = q0; pss[blk * H + c0 + 1] = q1;
}

// ---------------------------------------------------------------------------
// K3b: finalize mu/var -> scale/shift; also zero the loss accumulator.
// ---------------------------------------------------------------------------
__global__ __launch_bounds__(128) void k_finalize(
    const float* __restrict__ ps, const float* __restrict__ pss,
    const float* __restrict__ gamma, const float* __restrict__ beta,
    float* __restrict__ scale, float* __restrict__ shift,
    float* __restrict__ d_out) {
  const int c = blockIdx.x * 128 + threadIdx.x;
  if (c == 0) d_out[0] = 0.f;
  float s = 0, q = 0;
#pragma unroll 8
  for (int i = 0; i < 64; ++i) { s += ps[i * H + c]; q += pss[i * H + c]; }
  const float mu = s * (1.0f / NB);
  const float var = q * (1.0f / NB) - mu * mu;
  const float rstd = rsqrtf(var + EPS);
  const float sc = rstd * gamma[c];
  scale[c] = sc;
  shift[c] = beta[c] - mu * sc;
}

// ---------------------------------------------------------------------------
// K4: BN + ReLU + dot(w2) -> logits, fused BCE loss (1 atomic per block).
// ---------------------------------------------------------------------------
__global__ __launch_bounds__(256) void k_bn_dot_loss(
    const float* __restrict__ z, const float* __restrict__ scale,
    const float* __restrict__ shift, const float* __restrict__ w2,
    const float* __restrict__ b2, const float* __restrict__ t,
    float* __restrict__ out) {
  const int tid = threadIdx.x;
  const int wave = tid >> 6, lane = tid & 63;
  const int b = blockIdx.x * 4 + wave;
  const float4* __restrict__ z4 = (const float4*)(z + (size_t)b * H);
  const float4* __restrict__ sc4 = (const float4*)scale;
  const float4* __restrict__ sh4 = (const float4*)shift;
  const float4* __restrict__ w24 = (const float4*)w2;
  float acc = 0.f;
#pragma unroll
  for (int i = lane; i < 128; i += 64) {
    float4 zv = z4[i], sc = sc4[i], sh = sh4[i], w = w24[i];
    float h0 = fmaxf(zv.x * sc.x + sh.x, 0.f);
    float h1 = fmaxf(zv.y * sc.y + sh.y, 0.f);
    float h2 = fmaxf(zv.z * sc.z + sh.z, 0.f);
    float h3 = fmaxf(zv.w * sc.w + sh.w, 0.f);
    acc += h0 * w.x + h1 * w.y + h2 * w.z + h3 * w.w;
  }
#pragma unroll
  for (int off = 32; off > 0; off >>= 1) acc += __shfl_down(acc, off, 64);

  __shared__ float lred[4];
  if (lane == 0) {
    const float x = acc + b2[0];
    out[1 + b] = x;
    const float sp = fmaxf(x, 0.f) + log1pf(expf(-fabsf(x)));
    lred[wave] = sp - t[b] * x;
  }
  __syncthreads();
  if (tid == 0) {
    const float ls = (lred[0] + lred[1] + lred[2] + lred[3]) * (1.0f / NB);
    atomicAdd(out, ls);
  }
}

// ---------------------------------------------------------------------------
extern "C" void kernel_launch(void* const* d_in, const int* in_sizes, int n_in,
                              void* d_out, int out_size, void* d_ws, size_t ws_size,
                              hipStream_t stream) {
  const int*   tokens = (const int*)d_in[0];
  const int*   seg    = (const int*)d_in[1];
  const float* t      = (const float*)d_in[2];
  const float* emb    = (const float*)d_in[3];
  const float* W1     = (const float*)d_in[4];
  const float* b1     = (const float*)d_in[5];
  const float* gamma  = (const float*)d_in[6];
  const float* beta   = (const float*)d_in[7];
  const float* w2     = (const float*)d_in[8];
  const float* b2     = (const float*)d_in[9];
  float* out = (float*)d_out;

  // workspace layout (bytes)
  char* wsb = (char*)d_ws;
  half8*    embh   = (half8*)wsb;                          // 102,400,000
  _Float16* W1h    = (_Float16*)(wsb + 102400000);         // 524,288
  half8*    bow_h  = (half8*)(wsb + 102924288);            // 4,194,304
  float*    z      = (float*)(wsb + 107118592);            // 8,388,608
  float*    ps     = (float*)(wsb + 115507200);            // 131,072
  float*    pss    = ps + 64 * H;                          // 131,072
  float*    scale  = pss + 64 * H;                         // 2,048
  float*    shift  = scale + H;                            // 2,048
  int*      bounds = (int*)(shift + H);                    // (NB+1)*4

  k_seg_bounds<<<NTOK / 256, 256, 0, stream>>>(seg, bounds);
  k_convert<<<50000, 256, 0, stream>>>(emb, (h4*)embh);       // 100000*512/4
  k_convert<<<256, 256, 0, stream>>>(W1, (h4*)W1h);           // 512*512/4
  k_gather_mean<<<NB, 256, 0, stream>>>(tokens, bounds, embh, bow_h);
  k_gemm_mfma<<<512, 256, 0, stream>>>((const _Float16*)bow_h, W1h, b1, z);
  k_colstats<<<64, 256, 0, stream>>>(z, ps, pss);
  k_finalize<<<4, 128, 0, stream>>>(ps, pss, gamma, beta, scale, shift, out);
  k_bn_dot_loss<<<NB / 4, 256, 0, stream>>>(z, scale, shift, w2, b2, t, out);
}